// Round 1
// baseline (134.860 us; speedup 1.0000x reference)
//
#include <hip/hip_runtime.h>
#include <cstdint>

// Dynamic_MLP_C: fused bf16-MFMA implementation.
//
// Reformulation: x[t,o] = sum_k A[t,k] * B[k,o],  k = j*64+i  (K = 4160)
//   A[t, j*64+i] = w21[t,j] * w12[t,i]      (rank-1, built on the fly)
//   A[t, 4096+i] = w12[t,i]                 (bias rows)
//   B = [W22 viewed as [4096][64] ; b22 viewed as [64][64]]  (flat layouts match!)
//
// Kernel 1 (prep): weights -> bf16 in B-frag-native layout Bt[k>>3][o][k&7].
// Kernel 2 (main): per block = 128 tokens, 4 waves (32 tok/wave):
//   cat->LDS bf16 -> MFMA w11(relu) -> MFMA w21(relu) + w12 ->
//   K-loop: A-frags synthesized in registers, B double-buffered LDS chunks
//   (global_load_lds width=16) -> LN (shfl-xor) -> relu -> MFMA @W3 + b3.

typedef __bf16 bf16x8 __attribute__((ext_vector_type(8)));
typedef float  f32x4  __attribute__((ext_vector_type(4)));
typedef float  f32x8  __attribute__((ext_vector_type(8)));

#define MFMA16(A, B, C) __builtin_amdgcn_mfma_f32_16x16x32_bf16(A, B, C, 0, 0, 0)

// workspace element offsets (bf16 elements)
#define OFF_BT22 0         // K=4160, 266240 elems
#define OFF_W11  266240    // K=128,  8192
#define OFF_W21  274432    // K=128,  8192
#define OFF_W12  282624    // K=64,   4096
#define OFF_W3   286720    // K=64,   4096
#define WS_ELEMS 290816    // = 1136 * 256 exactly

__global__ __launch_bounds__(256) void prep_kernel(
    const float* __restrict__ W22, const float* __restrict__ b22,
    const float* __restrict__ W11, const float* __restrict__ W21,
    const float* __restrict__ W12, const float* __restrict__ W3,
    __bf16* __restrict__ ws)
{
    int gid = blockIdx.x * 256 + threadIdx.x;
    const float* src = nullptr; const float* srcb = nullptr;
    int base;
    if (gid < OFF_W11)      { base = OFF_BT22; src = W22; srcb = b22; }
    else if (gid < OFF_W12) { base = (gid < OFF_W21) ? OFF_W11 : OFF_W21;
                              src  = (gid < OFF_W21) ? W11 : W21; }
    else if (gid < OFF_W3)  { base = OFF_W12; src = W12; }
    else                    { base = OFF_W3;  src = W3;  }
    int d = gid - base;
    int kb = d >> 9, o = (d >> 3) & 63, kj = d & 7;
    int k = kb * 8 + kj;
    float v = (srcb && k >= 4096) ? srcb[(k - 4096) * 64 + o] : src[k * 64 + o];
    ws[gid] = (__bf16)v;
}

__global__ __launch_bounds__(256, 1) void main_kernel(
    const float* __restrict__ img, const float* __restrict__ loc,
    const float* __restrict__ b11, const float* __restrict__ b12,
    const float* __restrict__ b21, const float* __restrict__ ln_g,
    const float* __restrict__ ln_b, const float* __restrict__ b3,
    const __bf16* __restrict__ ws, float* __restrict__ out)
{
    // LDS carve (90112 B total):
    //  [0,34816)      catL [128][136] bf16; reused as B double-buf 2x16384
    //  [34816,53248)  w11L [128][72]  bf16; reused as xL (post-LN)
    //  [53248,71680)  w21L [128][72]  bf16
    //  [71680,90112)  w12L [128][72]  bf16
    __shared__ __align__(1024) char smem[90112];
    __bf16* catL = (__bf16*)smem;
    __bf16* w11L = (__bf16*)(smem + 34816);
    __bf16* w21L = (__bf16*)(smem + 53248);
    __bf16* w12L = (__bf16*)(smem + 71680);

    const int tid  = threadIdx.x;
    const int wv   = tid >> 6;
    const int lane = tid & 63;
    const int ln   = lane & 15;     // A-row / C-col / B-col lane index
    const int quad = lane >> 4;     // k-quad / C-row group
    const int wt   = wv * 32;       // block-local token base of this wave
    const long tb  = (long)blockIdx.x * 128;

    const __bf16* Bt22  = ws + OFF_BT22;
    const __bf16* W11bt = ws + OFF_W11;
    const __bf16* W21bt = ws + OFF_W21;
    const __bf16* W12bt = ws + OFF_W12;
    const __bf16* W3bt  = ws + OFF_W3;

    // ---------- P0: stage cat = [img | loc] as bf16 ----------
    {
        const float* srcs[2] = {img, loc};
        #pragma unroll
        for (int s = 0; s < 2; ++s) {
            const float* src = srcs[s] + tb * 64;
            #pragma unroll
            for (int it = 0; it < 8; ++it) {
                int u = (it * 256 + tid) * 4;         // 0..8188
                int t = u >> 6, c = u & 63;
                const float4 v = *(const float4*)(src + u);
                __bf16* p = catL + t * 136 + s * 64 + c;
                p[0] = (__bf16)v.x; p[1] = (__bf16)v.y;
                p[2] = (__bf16)v.z; p[3] = (__bf16)v.w;
            }
        }
    }
    __syncthreads();

    // ---------- P1: w11 = relu(cat@W11+b11), w21 = relu(cat@W21+b21) ----------
    {
        f32x4 a11[2][4] = {}; f32x4 a21[2][4] = {};
        #pragma unroll
        for (int kb = 0; kb < 4; ++kb) {
            bf16x8 af[2];
            #pragma unroll
            for (int mf = 0; mf < 2; ++mf)
                af[mf] = *(const bf16x8*)(catL + (wt + mf*16 + ln)*136 + kb*32 + quad*8);
            #pragma unroll
            for (int nf = 0; nf < 4; ++nf) {
                int o = nf*16 + ln;
                bf16x8 bw1 = *(const bf16x8*)(W11bt + ((kb*4 + quad)*64 + o)*8);
                bf16x8 bw2 = *(const bf16x8*)(W21bt + ((kb*4 + quad)*64 + o)*8);
                #pragma unroll
                for (int mf = 0; mf < 2; ++mf) {
                    a11[mf][nf] = MFMA16(af[mf], bw1, a11[mf][nf]);
                    a21[mf][nf] = MFMA16(af[mf], bw2, a21[mf][nf]);
                }
            }
        }
        #pragma unroll
        for (int nf = 0; nf < 4; ++nf) {
            int o = nf*16 + ln;
            float c11 = b11[o], c21 = b21[o];
            #pragma unroll
            for (int mf = 0; mf < 2; ++mf)
                #pragma unroll
                for (int r = 0; r < 4; ++r) {
                    int t = wt + mf*16 + quad*4 + r;
                    float v1 = a11[mf][nf][r] + c11; v1 = v1 > 0.f ? v1 : 0.f;
                    float v2 = a21[mf][nf][r] + c21; v2 = v2 > 0.f ? v2 : 0.f;
                    w11L[t*72 + o] = (__bf16)v1;
                    w21L[t*72 + o] = (__bf16)v2;
                }
        }
    }
    __syncthreads();

    // async B-chunk stager: chunk c = 4 k32-steps = 16 groups of 1 KB (tail: 8)
    auto stage = [&](int c) {
        const int ng = (c == 32) ? 8 : 16;
        char* buf = smem + (c & 1) * 16384;
        for (int g = wv; g < ng; g += 4) {
            const __bf16* gsrc = Bt22 + ((long)(c*16 + g) * 512) + lane * 8;
            void* ldst = buf + g * 1024;    // wave-uniform base; HW adds lane*16
            __builtin_amdgcn_global_load_lds(
                (const __attribute__((address_space(1))) uint32_t*)gsrc,
                (__attribute__((address_space(3))) uint32_t*)ldst, 16, 0, 0);
        }
    };
    stage(0);   // overlaps with P2

    // ---------- P2: w12 = w11@W12 + b12 (no relu) ----------
    {
        f32x4 a12c[2][4] = {};
        #pragma unroll
        for (int kb = 0; kb < 2; ++kb) {
            bf16x8 af[2];
            #pragma unroll
            for (int mf = 0; mf < 2; ++mf)
                af[mf] = *(const bf16x8*)(w11L + (wt + mf*16 + ln)*72 + kb*32 + quad*8);
            #pragma unroll
            for (int nf = 0; nf < 4; ++nf) {
                bf16x8 bw = *(const bf16x8*)(W12bt + ((kb*4 + quad)*64 + nf*16 + ln)*8);
                #pragma unroll
                for (int mf = 0; mf < 2; ++mf)
                    a12c[mf][nf] = MFMA16(af[mf], bw, a12c[mf][nf]);
            }
        }
        #pragma unroll
        for (int nf = 0; nf < 4; ++nf) {
            int o = nf*16 + ln;
            float c12 = b12[o];
            #pragma unroll
            for (int mf = 0; mf < 2; ++mf)
                #pragma unroll
                for (int r = 0; r < 4; ++r) {
                    int t = wt + mf*16 + quad*4 + r;
                    w12L[t*72 + o] = (__bf16)(a12c[mf][nf][r] + c12);
                }
        }
    }
    __syncthreads();    // w12L ready; chunk-0 loads drained by barrier

    // w12 row of this lane's A-rows, in A-fragment order (reused for all j, and
    // directly as the bias-block A-fragments)
    bf16x8 a12[2][2]; f32x8 w12f[2][2];
    #pragma unroll
    for (int mf = 0; mf < 2; ++mf)
        #pragma unroll
        for (int sub = 0; sub < 2; ++sub) {
            a12[mf][sub]  = *(const bf16x8*)(w12L + (wt + mf*16 + ln)*72 + sub*32 + quad*8);
            w12f[mf][sub] = __builtin_convertvector(a12[mf][sub], f32x8);
        }

    // ---------- P3: main K-loop over 33 chunks (32 regular + bias tail) ----------
    f32x4 acc[2][4] = {};
    for (int c = 0; c <= 32; ++c) {
        if (c < 32) stage(c + 1);
        const __bf16* buf = (const __bf16*)(smem + (c & 1) * 16384);
        if (c < 32) {
            #pragma unroll
            for (int kbl = 0; kbl < 4; ++kbl) {
                int j = c*2 + (kbl >> 1), sub = kbl & 1;
                bf16x8 af[2];
                #pragma unroll
                for (int mf = 0; mf < 2; ++mf) {
                    float wj = (float)w21L[(wt + mf*16 + ln)*72 + j];
                    af[mf] = __builtin_convertvector(w12f[mf][sub] * wj, bf16x8);
                }
                #pragma unroll
                for (int nf = 0; nf < 4; ++nf) {
                    bf16x8 bfr = *(const bf16x8*)(buf + (kbl*4 + quad)*512 + (nf*16 + ln)*8);
                    #pragma unroll
                    for (int mf = 0; mf < 2; ++mf)
                        acc[mf][nf] = MFMA16(af[mf], bfr, acc[mf][nf]);
                }
            }
        } else {
            // bias rows: A = w12 directly
            #pragma unroll
            for (int kbl = 0; kbl < 2; ++kbl)
                #pragma unroll
                for (int nf = 0; nf < 4; ++nf) {
                    bf16x8 bfr = *(const bf16x8*)(buf + (kbl*4 + quad)*512 + (nf*16 + ln)*8);
                    #pragma unroll
                    for (int mf = 0; mf < 2; ++mf)
                        acc[mf][nf] = MFMA16(a12[mf][kbl], bfr, acc[mf][nf]);
                }
        }
        __syncthreads();
    }

    // ---------- P4: LayerNorm(64) + relu, write x to LDS as bf16 ----------
    float gv[4], bv[4], b3v[4];
    #pragma unroll
    for (int nf = 0; nf < 4; ++nf) {
        int o = nf*16 + ln;
        gv[nf] = ln_g[o]; bv[nf] = ln_b[o]; b3v[nf] = b3[o];
    }
    __bf16* xL = w11L;   // reuse
    #pragma unroll
    for (int mf = 0; mf < 2; ++mf)
        #pragma unroll
        for (int r = 0; r < 4; ++r) {
            float s1 = 0.f, s2 = 0.f;
            #pragma unroll
            for (int nf = 0; nf < 4; ++nf) { float v = acc[mf][nf][r]; s1 += v; s2 += v*v; }
            #pragma unroll
            for (int d = 1; d < 16; d <<= 1) {   // token's 64 o-values live in 16 lanes (same quad)
                s1 += __shfl_xor(s1, d, 64);
                s2 += __shfl_xor(s2, d, 64);
            }
            float mean = s1 * 0.015625f;
            float var  = s2 * 0.015625f - mean * mean;
            float inv  = rsqrtf(var + 1e-5f);
            int t = wt + mf*16 + quad*4 + r;
            #pragma unroll
            for (int nf = 0; nf < 4; ++nf) {
                float v = (acc[mf][nf][r] - mean) * inv * gv[nf] + bv[nf];
                v = v > 0.f ? v : 0.f;
                xL[t*72 + nf*16 + ln] = (__bf16)v;
            }
        }
    __syncthreads();

    // ---------- P5: out = x @ W3 + b3 ----------
    f32x4 a3[2][4] = {};
    #pragma unroll
    for (int kb = 0; kb < 2; ++kb) {
        bf16x8 af[2];
        #pragma unroll
        for (int mf = 0; mf < 2; ++mf)
            af[mf] = *(const bf16x8*)(xL + (wt + mf*16 + ln)*72 + kb*32 + quad*8);
        #pragma unroll
        for (int nf = 0; nf < 4; ++nf) {
            bf16x8 bfr = *(const bf16x8*)(W3bt + ((kb*4 + quad)*64 + nf*16 + ln)*8);
            #pragma unroll
            for (int mf = 0; mf < 2; ++mf)
                a3[mf][nf] = MFMA16(af[mf], bfr, a3[mf][nf]);
        }
    }
    #pragma unroll
    for (int mf = 0; mf < 2; ++mf)
        #pragma unroll
        for (int nf = 0; nf < 4; ++nf)
            #pragma unroll
            for (int r = 0; r < 4; ++r) {
                long t = tb + wt + mf*16 + quad*4 + r;
                out[t*64 + nf*16 + ln] = a3[mf][nf][r] + b3v[nf];
            }
}

extern "C" void kernel_launch(void* const* d_in, const int* in_sizes, int n_in,
                              void* d_out, int out_size, void* d_ws, size_t ws_size,
                              hipStream_t stream)
{
    const float* img  = (const float*)d_in[0];
    const float* loc  = (const float*)d_in[1];
    const float* W11  = (const float*)d_in[2];
    const float* b11  = (const float*)d_in[3];
    const float* W12  = (const float*)d_in[4];
    const float* b12  = (const float*)d_in[5];
    const float* W21  = (const float*)d_in[6];
    const float* b21  = (const float*)d_in[7];
    const float* W22  = (const float*)d_in[8];
    const float* b22  = (const float*)d_in[9];
    const float* ln_g = (const float*)d_in[10];
    const float* ln_b = (const float*)d_in[11];
    const float* W3   = (const float*)d_in[12];
    const float* b3   = (const float*)d_in[13];
    __bf16* ws = (__bf16*)d_ws;
    float*  o  = (float*)d_out;

    prep_kernel<<<1136, 256, 0, stream>>>(W22, b22, W11, W21, W12, W3, ws);
    main_kernel<<<256, 256, 0, stream>>>(img, loc, b11, b12, b21, ln_g, ln_b, b3, ws, o);
}

// Round 2
// 133.049 us; speedup vs baseline: 1.0136x; 1.0136x over previous
//
#include <hip/hip_runtime.h>
#include <cstdint>

// Dynamic_MLP_C: fused bf16-MFMA implementation.
//
// Reformulation: x[t,o] = sum_k A[t,k] * B[k,o],  k = j*64+i  (K = 4160)
//   A[t, j*64+i] = w21[t,j] * w12[t,i]      (rank-1, built on the fly)
//   A[t, 4096+i] = w12[t,i]                 (bias rows)
//   B = [W22 viewed as [4096][64] ; b22 viewed as [64][64]]  (flat layouts match)
//
// R2 changes vs R1 (barrier/latency-bound, 3850 cyc/chunk wall vs ~800 pipe):
//  - K-chunk 128 -> 256: 17 __syncthreads (vmcnt drains) instead of 33.
//  - w21 chunk scalars: one ds_read_b64 per mf per chunk (was 8x ds_read_u16).
//  - prep kernel: coalesced LDS-tile transpose (was 64-way scattered reads).

typedef __bf16 bf16x4 __attribute__((ext_vector_type(4)));
typedef __bf16 bf16x8 __attribute__((ext_vector_type(8)));
typedef float  f32x4  __attribute__((ext_vector_type(4)));
typedef float  f32x8  __attribute__((ext_vector_type(8)));

#define MFMA16(A, B, C) __builtin_amdgcn_mfma_f32_16x16x32_bf16(A, B, C, 0, 0, 0)

// workspace element offsets (bf16 elements)
#define OFF_BT22 0         // K=4160, 266240 elems
#define OFF_W11  266240    // K=128,  8192
#define OFF_W21  274432    // K=128,  8192
#define OFF_W12  282624    // K=64,   4096
#define OFF_W3   286720    // K=64,   4096

// Coalesced transpose: each block converts one [64 k x 64 o] fp32 tile into
// B-frag-native bf16 layout dst[(k>>3)*512 + o*8 + (k&7)].
__global__ __launch_bounds__(256) void prep_kernel(
    const float* __restrict__ W22, const float* __restrict__ b22,
    const float* __restrict__ W11, const float* __restrict__ W21,
    const float* __restrict__ W12, const float* __restrict__ W3,
    __bf16* __restrict__ ws)
{
    __shared__ __bf16 T[64][72];
    const int b = blockIdx.x, tid = threadIdx.x;
    const float* src; __bf16* dst;
    if (b < 64)       { src = W22 + b * 4096;        dst = ws + OFF_BT22 + b * 4096; }
    else if (b == 64) { src = b22;                   dst = ws + OFF_BT22 + 64 * 4096; }
    else if (b < 67)  { src = W11 + (b - 65) * 4096; dst = ws + OFF_W11 + (b - 65) * 4096; }
    else if (b < 69)  { src = W21 + (b - 67) * 4096; dst = ws + OFF_W21 + (b - 67) * 4096; }
    else if (b == 69) { src = W12;                   dst = ws + OFF_W12; }
    else              { src = W3;                    dst = ws + OFF_W3; }
    #pragma unroll
    for (int it = 0; it < 4; ++it) {
        int u = it * 1024 + tid * 4;
        int r = u >> 6, c = u & 63;
        const float4 v = *(const float4*)(src + u);
        T[r][c] = (__bf16)v.x; T[r][c + 1] = (__bf16)v.y;
        T[r][c + 2] = (__bf16)v.z; T[r][c + 3] = (__bf16)v.w;
    }
    __syncthreads();
    #pragma unroll
    for (int it = 0; it < 2; ++it) {
        int item = it * 256 + tid;
        int q = item >> 6, o = item & 63;
        bf16x8 pk;
        #pragma unroll
        for (int kj = 0; kj < 8; ++kj) pk[kj] = T[q * 8 + kj][o];
        *(bf16x8*)(dst + q * 512 + o * 8) = pk;
    }
}

__global__ __launch_bounds__(256, 1) void main_kernel(
    const float* __restrict__ img, const float* __restrict__ loc,
    const float* __restrict__ b11, const float* __restrict__ b12,
    const float* __restrict__ b21, const float* __restrict__ ln_g,
    const float* __restrict__ ln_b, const float* __restrict__ b3,
    const __bf16* __restrict__ ws, float* __restrict__ out)
{
    // LDS carve (102400 B):
    //  [0,65536)       B double-buf, 2 x 32768 (chunk = K=256)
    //    [0,34816)     catL [128][136] bf16  (dead after P1, before stage(0))
    //    [34816,53248) w11L [128][72]  bf16  (dead after P2, before stage(1))
    //  [65536,83968)   w21L [128][72]  bf16  (alive through K-loop)
    //  [83968,102400)  w12L [128][72]  bf16  (dead after frag load; reused as xL)
    __shared__ __align__(1024) char smem[102400];
    __bf16* catL = (__bf16*)smem;
    __bf16* w11L = (__bf16*)(smem + 34816);
    __bf16* w21L = (__bf16*)(smem + 65536);
    __bf16* w12L = (__bf16*)(smem + 83968);

    const int tid  = threadIdx.x;
    const int wv   = tid >> 6;
    const int lane = tid & 63;
    const int ln   = lane & 15;     // A-row / C-col / B-col lane index
    const int quad = lane >> 4;     // k-quad / C-row group
    const int wt   = wv * 32;       // block-local token base of this wave
    const long tb  = (long)blockIdx.x * 128;

    const __bf16* Bt22  = ws + OFF_BT22;
    const __bf16* W11bt = ws + OFF_W11;
    const __bf16* W21bt = ws + OFF_W21;
    const __bf16* W12bt = ws + OFF_W12;
    const __bf16* W3bt  = ws + OFF_W3;

    // ---------- P0: stage cat = [img | loc] as bf16 ----------
    {
        const float* srcs[2] = {img, loc};
        #pragma unroll
        for (int s = 0; s < 2; ++s) {
            const float* src = srcs[s] + tb * 64;
            #pragma unroll
            for (int it = 0; it < 8; ++it) {
                int u = (it * 256 + tid) * 4;         // 0..8188
                int t = u >> 6, c = u & 63;
                const float4 v = *(const float4*)(src + u);
                bf16x4 pk = {(__bf16)v.x, (__bf16)v.y, (__bf16)v.z, (__bf16)v.w};
                *(bf16x4*)(catL + t * 136 + s * 64 + c) = pk;
            }
        }
    }
    __syncthreads();

    // ---------- P1: w11 = relu(cat@W11+b11), w21 = relu(cat@W21+b21) ----------
    {
        f32x4 a11[2][4] = {}; f32x4 a21[2][4] = {};
        #pragma unroll
        for (int kb = 0; kb < 4; ++kb) {
            bf16x8 af[2];
            #pragma unroll
            for (int mf = 0; mf < 2; ++mf)
                af[mf] = *(const bf16x8*)(catL + (wt + mf*16 + ln)*136 + kb*32 + quad*8);
            #pragma unroll
            for (int nf = 0; nf < 4; ++nf) {
                int o = nf*16 + ln;
                bf16x8 bw1 = *(const bf16x8*)(W11bt + ((kb*4 + quad)*64 + o)*8);
                bf16x8 bw2 = *(const bf16x8*)(W21bt + ((kb*4 + quad)*64 + o)*8);
                #pragma unroll
                for (int mf = 0; mf < 2; ++mf) {
                    a11[mf][nf] = MFMA16(af[mf], bw1, a11[mf][nf]);
                    a21[mf][nf] = MFMA16(af[mf], bw2, a21[mf][nf]);
                }
            }
        }
        #pragma unroll
        for (int nf = 0; nf < 4; ++nf) {
            int o = nf*16 + ln;
            float c11 = b11[o], c21 = b21[o];
            #pragma unroll
            for (int mf = 0; mf < 2; ++mf)
                #pragma unroll
                for (int r = 0; r < 4; ++r) {
                    int t = wt + mf*16 + quad*4 + r;
                    float v1 = a11[mf][nf][r] + c11; v1 = v1 > 0.f ? v1 : 0.f;
                    float v2 = a21[mf][nf][r] + c21; v2 = v2 > 0.f ? v2 : 0.f;
                    w11L[t*72 + o] = (__bf16)v1;
                    w21L[t*72 + o] = (__bf16)v2;
                }
        }
    }
    __syncthreads();

    // async B-chunk stager: chunk c = K=256 = 32 groups of 1 KB (tail c=16: 8)
    auto stage = [&](int c) {
        const int ng = (c == 16) ? 8 : 32;
        char* buf = smem + (c & 1) * 32768;
        for (int g = wv; g < ng; g += 4) {
            const __bf16* gsrc = Bt22 + ((long)c * 16384 + g * 512) + lane * 8;
            void* ldst = buf + g * 1024;    // wave-uniform base; HW adds lane*16
            __builtin_amdgcn_global_load_lds(
                (const __attribute__((address_space(1))) uint32_t*)gsrc,
                (__attribute__((address_space(3))) uint32_t*)ldst, 16, 0, 0);
        }
    };
    stage(0);   // overlaps with P2; writes buf0 (catL dead)

    // ---------- P2: w12 = w11@W12 + b12 (no relu) ----------
    {
        f32x4 a12c[2][4] = {};
        #pragma unroll
        for (int kb = 0; kb < 2; ++kb) {
            bf16x8 af[2];
            #pragma unroll
            for (int mf = 0; mf < 2; ++mf)
                af[mf] = *(const bf16x8*)(w11L + (wt + mf*16 + ln)*72 + kb*32 + quad*8);
            #pragma unroll
            for (int nf = 0; nf < 4; ++nf) {
                bf16x8 bw = *(const bf16x8*)(W12bt + ((kb*4 + quad)*64 + nf*16 + ln)*8);
                #pragma unroll
                for (int mf = 0; mf < 2; ++mf)
                    a12c[mf][nf] = MFMA16(af[mf], bw, a12c[mf][nf]);
            }
        }
        #pragma unroll
        for (int nf = 0; nf < 4; ++nf) {
            int o = nf*16 + ln;
            float c12 = b12[o];
            #pragma unroll
            for (int mf = 0; mf < 2; ++mf)
                #pragma unroll
                for (int r = 0; r < 4; ++r) {
                    int t = wt + mf*16 + quad*4 + r;
                    w12L[t*72 + o] = (__bf16)(a12c[mf][nf][r] + c12);
                }
        }
    }
    __syncthreads();    // w12L ready; chunk-0 loads drained by this barrier

    // w12 row of this lane's A-rows, in A-fragment order (reused for all j, and
    // directly as the bias-block A-fragments)
    bf16x8 a12[2][2]; f32x8 w12f[2][2];
    #pragma unroll
    for (int mf = 0; mf < 2; ++mf)
        #pragma unroll
        for (int sub = 0; sub < 2; ++sub) {
            a12[mf][sub]  = *(const bf16x8*)(w12L + (wt + mf*16 + ln)*72 + sub*32 + quad*8);
            w12f[mf][sub] = __builtin_convertvector(a12[mf][sub], f32x8);
        }

    // ---------- P3: main K-loop over 17 chunks (16 x K=256 + bias tail) ----------
    f32x4 acc[2][4] = {};
    for (int c = 0; c <= 16; ++c) {
        if (c < 16) stage(c + 1);
        const __bf16* buf = (const __bf16*)(smem + (c & 1) * 32768);
        if (c < 16) {
            // this chunk's 4 w21 scalars per A-row: one b64 per mf
            bf16x4 w21v[2];
            #pragma unroll
            for (int mf = 0; mf < 2; ++mf)
                w21v[mf] = *(const bf16x4*)(w21L + (wt + mf*16 + ln)*72 + c*4);
            #pragma unroll
            for (int s = 0; s < 8; ++s) {
                int sub = s & 1;
                bf16x8 af[2];
                #pragma unroll
                for (int mf = 0; mf < 2; ++mf) {
                    float wj = (float)w21v[mf][s >> 1];
                    af[mf] = __builtin_convertvector(w12f[mf][sub] * wj, bf16x8);
                }
                #pragma unroll
                for (int nf = 0; nf < 4; ++nf) {
                    bf16x8 bfr = *(const bf16x8*)(buf + (s*4 + quad)*512 + (nf*16 + ln)*8);
                    #pragma unroll
                    for (int mf = 0; mf < 2; ++mf)
                        acc[mf][nf] = MFMA16(af[mf], bfr, acc[mf][nf]);
                }
            }
        } else {
            // bias rows: A = w12 directly
            #pragma unroll
            for (int s = 0; s < 2; ++s)
                #pragma unroll
                for (int nf = 0; nf < 4; ++nf) {
                    bf16x8 bfr = *(const bf16x8*)(buf + (s*4 + quad)*512 + (nf*16 + ln)*8);
                    #pragma unroll
                    for (int mf = 0; mf < 2; ++mf)
                        acc[mf][nf] = MFMA16(a12[mf][s], bfr, acc[mf][nf]);
                }
        }
        __syncthreads();
    }

    // ---------- P4: LayerNorm(64) + relu, write x to LDS as bf16 ----------
    float gv[4], bv[4], b3v[4];
    #pragma unroll
    for (int nf = 0; nf < 4; ++nf) {
        int o = nf*16 + ln;
        gv[nf] = ln_g[o]; bv[nf] = ln_b[o]; b3v[nf] = b3[o];
    }
    __bf16* xL = w12L;   // reuse (w12L dead after frag load)
    #pragma unroll
    for (int mf = 0; mf < 2; ++mf)
        #pragma unroll
        for (int r = 0; r < 4; ++r) {
            float s1 = 0.f, s2 = 0.f;
            #pragma unroll
            for (int nf = 0; nf < 4; ++nf) { float v = acc[mf][nf][r]; s1 += v; s2 += v*v; }
            #pragma unroll
            for (int d = 1; d < 16; d <<= 1) {   // token's 64 o-values live in 16 lanes
                s1 += __shfl_xor(s1, d, 64);
                s2 += __shfl_xor(s2, d, 64);
            }
            float mean = s1 * 0.015625f;
            float var  = s2 * 0.015625f - mean * mean;
            float inv  = rsqrtf(var + 1e-5f);
            int t = wt + mf*16 + quad*4 + r;
            #pragma unroll
            for (int nf = 0; nf < 4; ++nf) {
                float v = (acc[mf][nf][r] - mean) * inv * gv[nf] + bv[nf];
                v = v > 0.f ? v : 0.f;
                xL[t*72 + nf*16 + ln] = (__bf16)v;
            }
        }
    __syncthreads();

    // ---------- P5: out = x @ W3 + b3 ----------
    f32x4 a3[2][4] = {};
    #pragma unroll
    for (int kb = 0; kb < 2; ++kb) {
        bf16x8 af[2];
        #pragma unroll
        for (int mf = 0; mf < 2; ++mf)
            af[mf] = *(const bf16x8*)(xL + (wt + mf*16 + ln)*72 + kb*32 + quad*8);
        #pragma unroll
        for (int nf = 0; nf < 4; ++nf) {
            bf16x8 bfr = *(const bf16x8*)(W3bt + ((kb*4 + quad)*64 + nf*16 + ln)*8);
            #pragma unroll
            for (int mf = 0; mf < 2; ++mf)
                a3[mf][nf] = MFMA16(af[mf], bfr, a3[mf][nf]);
        }
    }
    #pragma unroll
    for (int mf = 0; mf < 2; ++mf)
        #pragma unroll
        for (int nf = 0; nf < 4; ++nf)
            #pragma unroll
            for (int r = 0; r < 4; ++r) {
                long t = tb + wt + mf*16 + quad*4 + r;
                out[t*64 + nf*16 + ln] = a3[mf][nf][r] + b3v[nf];
            }
}

extern "C" void kernel_launch(void* const* d_in, const int* in_sizes, int n_in,
                              void* d_out, int out_size, void* d_ws, size_t ws_size,
                              hipStream_t stream)
{
    const float* img  = (const float*)d_in[0];
    const float* loc  = (const float*)d_in[1];
    const float* W11  = (const float*)d_in[2];
    const float* b11  = (const float*)d_in[3];
    const float* W12  = (const float*)d_in[4];
    const float* b12  = (const float*)d_in[5];
    const float* W21  = (const float*)d_in[6];
    const float* b21  = (const float*)d_in[7];
    const float* W22  = (const float*)d_in[8];
    const float* b22  = (const float*)d_in[9];
    const float* ln_g = (const float*)d_in[10];
    const float* ln_b = (const float*)d_in[11];
    const float* W3   = (const float*)d_in[12];
    const float* b3   = (const float*)d_in[13];
    __bf16* ws = (__bf16*)d_ws;
    float*  o  = (float*)d_out;

    prep_kernel<<<71, 256, 0, stream>>>(W22, b22, W11, W21, W12, W3, ws);
    main_kernel<<<256, 256, 0, stream>>>(img, loc, b11, b12, b21, ln_g, ln_b, b3, ws, o);
}

// Round 3
// 128.367 us; speedup vs baseline: 1.0506x; 1.0365x over previous
//
#include <hip/hip_runtime.h>
#include <cstdint>

// Dynamic_MLP_C: fused bf16-MFMA implementation.
//
// Reformulation: x[t,o] = sum_k A[t,k] * B[k,o],  k = j*64+i  (K = 4160)
//   A[t, j*64+i] = w21[t,j] * w12[t,i]      (rank-1, built on the fly)
//   A[t, 4096+i] = w12[t,i]                 (bias rows)
//   B = [W22 viewed as [4096][64] ; b22 viewed as [64][64]]  (flat layouts match)
//
// R3: latency-bound diagnosis -> overlap via occupancy.
//  - 512 blocks x 64 tokens, LDS 60 KB -> 2 blocks/CU: one block computes
//    while the other drains its barrier vmcnt(0).
//  - wave = 32 tokens x 32 o-cols (mf=2, nf=2): per-wave B LDS traffic halves
//    (266 KB), keeping the per-CU LDS floor ~10 us at 8 waves/CU.
//  - LN: cross-wave partial-sum exchange through 1 KB LDS (o split across waves).

typedef __bf16 bf16x2 __attribute__((ext_vector_type(2)));
typedef __bf16 bf16x4 __attribute__((ext_vector_type(4)));
typedef __bf16 bf16x8 __attribute__((ext_vector_type(8)));
typedef float  f32x4  __attribute__((ext_vector_type(4)));
typedef float  f32x8  __attribute__((ext_vector_type(8)));

#define MFMA16(A, B, C) __builtin_amdgcn_mfma_f32_16x16x32_bf16(A, B, C, 0, 0, 0)

// workspace element offsets (bf16 elements)
#define OFF_BT22 0         // K=4160, 266240 elems
#define OFF_W11  266240    // K=128,  8192
#define OFF_W21  274432    // K=128,  8192
#define OFF_W12  282624    // K=64,   4096
#define OFF_W3   286720    // K=64,   4096

// Coalesced transpose: each block converts one [64 k x 64 o] fp32 tile into
// B-frag-native bf16 layout dst[(k>>3)*512 + o*8 + (k&7)].
__global__ __launch_bounds__(256) void prep_kernel(
    const float* __restrict__ W22, const float* __restrict__ b22,
    const float* __restrict__ W11, const float* __restrict__ W21,
    const float* __restrict__ W12, const float* __restrict__ W3,
    __bf16* __restrict__ ws)
{
    __shared__ __bf16 T[64][72];
    const int b = blockIdx.x, tid = threadIdx.x;
    const float* src; __bf16* dst;
    if (b < 64)       { src = W22 + b * 4096;        dst = ws + OFF_BT22 + b * 4096; }
    else if (b == 64) { src = b22;                   dst = ws + OFF_BT22 + 64 * 4096; }
    else if (b < 67)  { src = W11 + (b - 65) * 4096; dst = ws + OFF_W11 + (b - 65) * 4096; }
    else if (b < 69)  { src = W21 + (b - 67) * 4096; dst = ws + OFF_W21 + (b - 67) * 4096; }
    else if (b == 69) { src = W12;                   dst = ws + OFF_W12; }
    else              { src = W3;                    dst = ws + OFF_W3; }
    #pragma unroll
    for (int it = 0; it < 4; ++it) {
        int u = it * 1024 + tid * 4;
        int r = u >> 6, c = u & 63;
        const float4 v = *(const float4*)(src + u);
        T[r][c] = (__bf16)v.x; T[r][c + 1] = (__bf16)v.y;
        T[r][c + 2] = (__bf16)v.z; T[r][c + 3] = (__bf16)v.w;
    }
    __syncthreads();
    #pragma unroll
    for (int it = 0; it < 2; ++it) {
        int item = it * 256 + tid;
        int q = item >> 6, o = item & 63;
        bf16x8 pk;
        #pragma unroll
        for (int kj = 0; kj < 8; ++kj) pk[kj] = T[q * 8 + kj][o];
        *(bf16x8*)(dst + q * 512 + o * 8) = pk;
    }
}

__global__ __launch_bounds__(256, 2) void main_kernel(
    const float* __restrict__ img, const float* __restrict__ loc,
    const float* __restrict__ b11, const float* __restrict__ b12,
    const float* __restrict__ b21, const float* __restrict__ ln_g,
    const float* __restrict__ ln_b, const float* __restrict__ b3,
    const __bf16* __restrict__ ws, float* __restrict__ out)
{
    // LDS carve (61440 B, 2 blocks/CU):
    //  [0,32768)      B double-buf 2x16384 (K=128 chunks)
    //    [0,17408)    catL [64][136] bf16 (dead after P1; staging starts after)
    //  [32768,41984)  w11L [64][72] bf16  (dead after P2)
    //  [41984,51200)  w21L [64][72] bf16  (alive through K-loop)
    //  [51200,60416)  w12L [64][72] bf16  (dead after frag load; reused as xL)
    //  [60416,61440)  ps   [64][2] float2 (LN cross-wave partials)
    __shared__ __align__(1024) char smem[61440];
    __bf16* catL = (__bf16*)smem;
    __bf16* w11L = (__bf16*)(smem + 32768);
    __bf16* w21L = (__bf16*)(smem + 41984);
    __bf16* w12L = (__bf16*)(smem + 51200);
    float2* ps   = (float2*)(smem + 60416);

    const int tid  = threadIdx.x;
    const int wv   = tid >> 6;
    const int lane = tid & 63;
    const int ln   = lane & 15;     // A-row / C-col / B-col lane index
    const int quad = lane >> 4;     // k-quad / C-row group
    const int th   = wv & 1;        // token half (32 tokens)
    const int oh   = wv >> 1;       // o half (32 cols)
    const int wt   = th * 32;       // block-local token base
    const int ob   = oh * 32;       // o-col base
    const long tb  = (long)blockIdx.x * 64;

    const __bf16* Bt22  = ws + OFF_BT22;
    const __bf16* W11bt = ws + OFF_W11;
    const __bf16* W21bt = ws + OFF_W21;
    const __bf16* W12bt = ws + OFF_W12;
    const __bf16* W3bt  = ws + OFF_W3;

    // ---------- P0: stage cat = [img | loc] as bf16 (64 tokens) ----------
    {
        const float* srcs[2] = {img, loc};
        #pragma unroll
        for (int s = 0; s < 2; ++s) {
            const float* src = srcs[s] + tb * 64;
            #pragma unroll
            for (int it = 0; it < 4; ++it) {
                int u = (it * 256 + tid) * 4;         // 0..4092
                int t = u >> 6, c = u & 63;
                const float4 v = *(const float4*)(src + u);
                bf16x4 pk = {(__bf16)v.x, (__bf16)v.y, (__bf16)v.z, (__bf16)v.w};
                *(bf16x4*)(catL + t * 136 + s * 64 + c) = pk;
            }
        }
    }
    __syncthreads();

    // ---------- P1: waves oh=0 -> w11 = relu(cat@W11+b11) for all 64 tokens,
    //               waves oh=1 -> w21 = relu(cat@W21+b21) ----------
    {
        const __bf16* Wbt = oh ? W21bt : W11bt;
        const float* bsel = oh ? b21 : b11;
        __bf16* tgtL      = oh ? w21L : w11L;
        f32x4 a1[2][4] = {};
        #pragma unroll
        for (int kb = 0; kb < 4; ++kb) {
            bf16x8 af[2];
            #pragma unroll
            for (int mf = 0; mf < 2; ++mf)
                af[mf] = *(const bf16x8*)(catL + (wt + mf*16 + ln)*136 + kb*32 + quad*8);
            #pragma unroll
            for (int nf = 0; nf < 4; ++nf) {
                bf16x8 bw = *(const bf16x8*)(Wbt + ((kb*4 + quad)*64 + nf*16 + ln)*8);
                #pragma unroll
                for (int mf = 0; mf < 2; ++mf)
                    a1[mf][nf] = MFMA16(af[mf], bw, a1[mf][nf]);
            }
        }
        #pragma unroll
        for (int nf = 0; nf < 4; ++nf) {
            int o = nf*16 + ln;
            float cb = bsel[o];
            #pragma unroll
            for (int mf = 0; mf < 2; ++mf)
                #pragma unroll
                for (int r = 0; r < 4; ++r) {
                    int t = wt + mf*16 + quad*4 + r;
                    float v = a1[mf][nf][r] + cb; v = v > 0.f ? v : 0.f;
                    tgtL[t*72 + o] = (__bf16)v;
                }
        }
    }
    __syncthreads();

    // async B-chunk stager: chunk c = K=128 = 16 groups of 1 KB (tail c=32: 8)
    auto stage = [&](int c) {
        const int ng = (c == 32) ? 8 : 16;
        char* buf = smem + (c & 1) * 16384;
        for (int g = wv; g < ng; g += 4) {
            const __bf16* gsrc = Bt22 + ((long)c * 8192 + g * 512) + lane * 8;
            void* ldst = buf + g * 1024;    // wave-uniform base; HW adds lane*16
            __builtin_amdgcn_global_load_lds(
                (const __attribute__((address_space(1))) uint32_t*)gsrc,
                (__attribute__((address_space(3))) uint32_t*)ldst, 16, 0, 0);
        }
    };
    stage(0);   // overlaps with P2; writes buf0 (catL dead)

    // ---------- P2: w12 = w11@W12 + b12 (no relu), quarter per wave ----------
    {
        f32x4 a12c[2][2] = {};
        #pragma unroll
        for (int kb = 0; kb < 2; ++kb) {
            bf16x8 af[2];
            #pragma unroll
            for (int mf = 0; mf < 2; ++mf)
                af[mf] = *(const bf16x8*)(w11L + (wt + mf*16 + ln)*72 + kb*32 + quad*8);
            #pragma unroll
            for (int nf = 0; nf < 2; ++nf) {
                bf16x8 bw = *(const bf16x8*)(W12bt + ((kb*4 + quad)*64 + ob + nf*16 + ln)*8);
                #pragma unroll
                for (int mf = 0; mf < 2; ++mf)
                    a12c[mf][nf] = MFMA16(af[mf], bw, a12c[mf][nf]);
            }
        }
        #pragma unroll
        for (int nf = 0; nf < 2; ++nf) {
            int o = ob + nf*16 + ln;
            float c12 = b12[o];
            #pragma unroll
            for (int mf = 0; mf < 2; ++mf)
                #pragma unroll
                for (int r = 0; r < 4; ++r) {
                    int t = wt + mf*16 + quad*4 + r;
                    w12L[t*72 + o] = (__bf16)(a12c[mf][nf][r] + c12);
                }
        }
    }
    __syncthreads();    // w12L ready; chunk-0 loads drained by this barrier

    // w12 row of this lane's A-rows, A-fragment order (reused for all j; also
    // directly the bias-block A-fragments)
    bf16x8 a12[2][2]; f32x8 w12f[2][2];
    #pragma unroll
    for (int mf = 0; mf < 2; ++mf)
        #pragma unroll
        for (int sub = 0; sub < 2; ++sub) {
            a12[mf][sub]  = *(const bf16x8*)(w12L + (wt + mf*16 + ln)*72 + sub*32 + quad*8);
            w12f[mf][sub] = __builtin_convertvector(a12[mf][sub], f32x8);
        }

    // ---------- P3: K-loop over 33 chunks (32 x K=128 + bias tail) ----------
    f32x4 acc[2][2] = {};
    for (int c = 0; c <= 32; ++c) {
        if (c < 32) stage(c + 1);
        const __bf16* buf = (const __bf16*)(smem + (c & 1) * 16384);
        if (c < 32) {
            // this chunk's 2 w21 scalars (j = 2c, 2c+1) per A-row: one b32/mf
            bf16x2 w21v[2];
            #pragma unroll
            for (int mf = 0; mf < 2; ++mf)
                w21v[mf] = *(const bf16x2*)(w21L + (wt + mf*16 + ln)*72 + c*2);
            #pragma unroll
            for (int s = 0; s < 4; ++s) {
                int sub = s & 1;
                bf16x8 af[2];
                #pragma unroll
                for (int mf = 0; mf < 2; ++mf) {
                    float wj = (float)w21v[mf][s >> 1];
                    af[mf] = __builtin_convertvector(w12f[mf][sub] * wj, bf16x8);
                }
                #pragma unroll
                for (int nf = 0; nf < 2; ++nf) {
                    bf16x8 bfr = *(const bf16x8*)(buf + (s*4 + quad)*512 + (ob + nf*16 + ln)*8);
                    #pragma unroll
                    for (int mf = 0; mf < 2; ++mf)
                        acc[mf][nf] = MFMA16(af[mf], bfr, acc[mf][nf]);
                }
            }
        } else {
            // bias rows: A = w12 directly
            #pragma unroll
            for (int s = 0; s < 2; ++s)
                #pragma unroll
                for (int nf = 0; nf < 2; ++nf) {
                    bf16x8 bfr = *(const bf16x8*)(buf + (s*4 + quad)*512 + (ob + nf*16 + ln)*8);
                    #pragma unroll
                    for (int mf = 0; mf < 2; ++mf)
                        acc[mf][nf] = MFMA16(a12[mf][s], bfr, acc[mf][nf]);
                }
        }
        __syncthreads();
    }

    // ---------- P4: LayerNorm(64) + relu (o split across waves -> LDS partials) ----------
    #pragma unroll
    for (int mf = 0; mf < 2; ++mf)
        #pragma unroll
        for (int r = 0; r < 4; ++r) {
            float s1 = 0.f, s2 = 0.f;
            #pragma unroll
            for (int nf = 0; nf < 2; ++nf) { float v = acc[mf][nf][r]; s1 += v; s2 += v*v; }
            #pragma unroll
            for (int d = 1; d < 16; d <<= 1) {   // reduce over the 16 lanes of this quad
                s1 += __shfl_xor(s1, d, 64);
                s2 += __shfl_xor(s2, d, 64);
            }
            if (ln == 0) {
                int t = wt + mf*16 + quad*4 + r;
                ps[t*2 + oh] = make_float2(s1, s2);
            }
        }
    __syncthreads();

    float gv[2], bv[2], b3v[2];
    #pragma unroll
    for (int nf = 0; nf < 2; ++nf) {
        int o = ob + nf*16 + ln;
        gv[nf] = ln_g[o]; bv[nf] = ln_b[o]; b3v[nf] = b3[o];
    }
    __bf16* xL = w12L;   // reuse
    #pragma unroll
    for (int mf = 0; mf < 2; ++mf)
        #pragma unroll
        for (int r = 0; r < 4; ++r) {
            int t = wt + mf*16 + quad*4 + r;
            float2 p0 = ps[t*2], p1 = ps[t*2 + 1];
            float mean = (p0.x + p1.x) * 0.015625f;
            float var  = (p0.y + p1.y) * 0.015625f - mean * mean;
            float inv  = rsqrtf(var + 1e-5f);
            #pragma unroll
            for (int nf = 0; nf < 2; ++nf) {
                float v = (acc[mf][nf][r] - mean) * inv * gv[nf] + bv[nf];
                v = v > 0.f ? v : 0.f;
                xL[t*72 + ob + nf*16 + ln] = (__bf16)v;
            }
        }
    __syncthreads();

    // ---------- P5: out = x @ W3 + b3 (quarter per wave) ----------
    f32x4 a3[2][2] = {};
    #pragma unroll
    for (int kb = 0; kb < 2; ++kb) {
        bf16x8 af[2];
        #pragma unroll
        for (int mf = 0; mf < 2; ++mf)
            af[mf] = *(const bf16x8*)(xL + (wt + mf*16 + ln)*72 + kb*32 + quad*8);
        #pragma unroll
        for (int nf = 0; nf < 2; ++nf) {
            bf16x8 bfr = *(const bf16x8*)(W3bt + ((kb*4 + quad)*64 + ob + nf*16 + ln)*8);
            #pragma unroll
            for (int mf = 0; mf < 2; ++mf)
                a3[mf][nf] = MFMA16(af[mf], bfr, a3[mf][nf]);
        }
    }
    #pragma unroll
    for (int mf = 0; mf < 2; ++mf)
        #pragma unroll
        for (int nf = 0; nf < 2; ++nf)
            #pragma unroll
            for (int r = 0; r < 4; ++r) {
                long t = tb + wt + mf*16 + quad*4 + r;
                out[t*64 + ob + nf*16 + ln] = a3[mf][nf][r] + b3v[nf];
            }
}

extern "C" void kernel_launch(void* const* d_in, const int* in_sizes, int n_in,
                              void* d_out, int out_size, void* d_ws, size_t ws_size,
                              hipStream_t stream)
{
    const float* img  = (const float*)d_in[0];
    const float* loc  = (const float*)d_in[1];
    const float* W11  = (const float*)d_in[2];
    const float* b11  = (const float*)d_in[3];
    const float* W12  = (const float*)d_in[4];
    const float* b12  = (const float*)d_in[5];
    const float* W21  = (const float*)d_in[6];
    const float* b21  = (const float*)d_in[7];
    const float* W22  = (const float*)d_in[8];
    const float* b22  = (const float*)d_in[9];
    const float* ln_g = (const float*)d_in[10];
    const float* ln_b = (const float*)d_in[11];
    const float* W3   = (const float*)d_in[12];
    const float* b3   = (const float*)d_in[13];
    __bf16* ws = (__bf16*)d_ws;
    float*  o  = (float*)d_out;

    prep_kernel<<<71, 256, 0, stream>>>(W22, b22, W11, W21, W12, W3, ws);
    main_kernel<<<512, 256, 0, stream>>>(img, loc, b11, b12, b21, ln_g, ln_b, b3, ws, o);
}

// Round 5
// 126.293 us; speedup vs baseline: 1.0678x; 1.0164x over previous
//
#include <hip/hip_runtime.h>
#include <cstdint>

// Dynamic_MLP_C: fused bf16-MFMA implementation.
//
// Reformulation: x[t,o] = sum_k A[t,k] * B[k,o],  k = j*64+i  (K = 4160)
//   with A[t, j*64+i] = w21[t,j] * w12[t,i]  (rank-1), bias rows A[t,4096+i]=w12[t,i].
// R4 re-association: x[t,o] = sum_j w21[t,j] * (w12[t,:] @ B_j)[o]
//   -> A-fragment is the CONSTANT w12 register fragment (no per-chunk synth);
//      per j: 2 MFMAs -> m, then acc += w21[t,j]*m (w21 read in C-layout from
//      transposed LDS store w21T[j][t]).
// R4 pipeline: depth-2 prefetch, triple-buffered B, raw s_barrier with manual
//   s_waitcnt vmcnt(N) so chunk c+2 loads stay IN FLIGHT across the barrier
//   (the m97-structure vmcnt(0) drain was the exposed-latency culprit).
// R5: fix macro/braced-initializer compile error (named zero vector).

typedef __bf16 bf16x4 __attribute__((ext_vector_type(4)));
typedef __bf16 bf16x8 __attribute__((ext_vector_type(8)));
typedef float  f32x4  __attribute__((ext_vector_type(4)));

#define MFMA16(A, B, C) __builtin_amdgcn_mfma_f32_16x16x32_bf16(A, B, C, 0, 0, 0)

// raw pipeline barrier: drain own loads down to N, then barrier. c+2 chunk's
// loads (N newest) remain outstanding across it.
#define SYNC_PIPE(N) asm volatile("s_waitcnt vmcnt(" #N ")\n\ts_barrier" ::: "memory")

// workspace element offsets (bf16 elements)
#define OFF_BT22 0         // K=4160, 266240 elems
#define OFF_W11  266240    // K=128,  8192
#define OFF_W21  274432    // K=128,  8192
#define OFF_W12  282624    // K=64,   4096
#define OFF_W3   286720    // K=64,   4096

// Coalesced transpose: each block converts one [64 k x 64 o] fp32 tile into
// B-frag-native bf16 layout dst[(k>>3)*512 + o*8 + (k&7)].
__global__ __launch_bounds__(256) void prep_kernel(
    const float* __restrict__ W22, const float* __restrict__ b22,
    const float* __restrict__ W11, const float* __restrict__ W21,
    const float* __restrict__ W12, const float* __restrict__ W3,
    __bf16* __restrict__ ws)
{
    __shared__ __bf16 T[64][72];
    const int b = blockIdx.x, tid = threadIdx.x;
    const float* src; __bf16* dst;
    if (b < 64)       { src = W22 + b * 4096;        dst = ws + OFF_BT22 + b * 4096; }
    else if (b == 64) { src = b22;                   dst = ws + OFF_BT22 + 64 * 4096; }
    else if (b < 67)  { src = W11 + (b - 65) * 4096; dst = ws + OFF_W11 + (b - 65) * 4096; }
    else if (b < 69)  { src = W21 + (b - 67) * 4096; dst = ws + OFF_W21 + (b - 67) * 4096; }
    else if (b == 69) { src = W12;                   dst = ws + OFF_W12; }
    else              { src = W3;                    dst = ws + OFF_W3; }
    #pragma unroll
    for (int it = 0; it < 4; ++it) {
        int u = it * 1024 + tid * 4;
        int r = u >> 6, c = u & 63;
        const float4 v = *(const float4*)(src + u);
        T[r][c] = (__bf16)v.x; T[r][c + 1] = (__bf16)v.y;
        T[r][c + 2] = (__bf16)v.z; T[r][c + 3] = (__bf16)v.w;
    }
    __syncthreads();
    #pragma unroll
    for (int it = 0; it < 2; ++it) {
        int item = it * 256 + tid;
        int q = item >> 6, o = item & 63;
        bf16x8 pk;
        #pragma unroll
        for (int kj = 0; kj < 8; ++kj) pk[kj] = T[q * 8 + kj][o];
        *(bf16x8*)(dst + q * 512 + o * 8) = pk;
    }
}

__global__ __launch_bounds__(256, 2) void main_kernel(
    const float* __restrict__ img, const float* __restrict__ loc,
    const float* __restrict__ b11, const float* __restrict__ b12,
    const float* __restrict__ b21, const float* __restrict__ ln_g,
    const float* __restrict__ ln_b, const float* __restrict__ b3,
    const __bf16* __restrict__ ws, float* __restrict__ out)
{
    // LDS carve (77824 B, 2 blocks/CU):
    //  [0,49152)      B triple-buf 3x16384 (K=128 chunks)
    //    [0,17408)    catL [64][136] bf16 (dead after P1; staging starts after)
    //  [49152,58368)  w11L [64][72] bf16   (written P1, read P2)
    //  [58368,67584)  w21T [64 j][72 t] bf16 TRANSPOSED (read in K-loop, C-layout)
    //  [67584,76800)  w12L [64][72] bf16   (read for a12 frags; reused as xL)
    //  [76800,77824)  ps   [64][2] float2  (LN cross-wave partials)
    __shared__ __align__(1024) char smem[77824];
    __bf16* catL = (__bf16*)smem;
    __bf16* w11L = (__bf16*)(smem + 49152);
    __bf16* w21T = (__bf16*)(smem + 58368);
    __bf16* w12L = (__bf16*)(smem + 67584);
    float2* ps   = (float2*)(smem + 76800);

    const int tid  = threadIdx.x;
    const int wv   = tid >> 6;
    const int lane = tid & 63;
    const int ln   = lane & 15;     // A-row / C-col / B-col lane index
    const int quad = lane >> 4;     // k-quad / C-row group
    const int th   = wv & 1;        // token half (32 tokens)
    const int oh   = wv >> 1;       // o half (32 cols)
    const int wt   = th * 32;       // block-local token base
    const int ob   = oh * 32;       // o-col base
    const long tb  = (long)blockIdx.x * 64;

    const __bf16* Bt22  = ws + OFF_BT22;
    const __bf16* W11bt = ws + OFF_W11;
    const __bf16* W21bt = ws + OFF_W21;
    const __bf16* W12bt = ws + OFF_W12;
    const __bf16* W3bt  = ws + OFF_W3;

    // ---------- P0: stage cat = [img | loc] as bf16 (64 tokens) ----------
    {
        const float* srcs[2] = {img, loc};
        #pragma unroll
        for (int s = 0; s < 2; ++s) {
            const float* src = srcs[s] + tb * 64;
            #pragma unroll
            for (int it = 0; it < 4; ++it) {
                int u = (it * 256 + tid) * 4;         // 0..4092
                int t = u >> 6, c = u & 63;
                const float4 v = *(const float4*)(src + u);
                bf16x4 pk = {(__bf16)v.x, (__bf16)v.y, (__bf16)v.z, (__bf16)v.w};
                *(bf16x4*)(catL + t * 136 + s * 64 + c) = pk;
            }
        }
    }
    __syncthreads();

    // ---------- P1: waves oh=0 -> w11 (A-layout), oh=1 -> w21 (TRANSPOSED) ----------
    {
        const __bf16* Wbt = oh ? W21bt : W11bt;
        const float* bsel = oh ? b21 : b11;
        f32x4 a1[2][4] = {};
        #pragma unroll
        for (int kb = 0; kb < 4; ++kb) {
            bf16x8 af[2];
            #pragma unroll
            for (int mf = 0; mf < 2; ++mf)
                af[mf] = *(const bf16x8*)(catL + (wt + mf*16 + ln)*136 + kb*32 + quad*8);
            #pragma unroll
            for (int nf = 0; nf < 4; ++nf) {
                bf16x8 bw = *(const bf16x8*)(Wbt + ((kb*4 + quad)*64 + nf*16 + ln)*8);
                #pragma unroll
                for (int mf = 0; mf < 2; ++mf)
                    a1[mf][nf] = MFMA16(af[mf], bw, a1[mf][nf]);
            }
        }
        if (oh == 0) {
            #pragma unroll
            for (int nf = 0; nf < 4; ++nf) {
                int o = nf*16 + ln;
                float cb = bsel[o];
                #pragma unroll
                for (int mf = 0; mf < 2; ++mf)
                    #pragma unroll
                    for (int r = 0; r < 4; ++r) {
                        int t = wt + mf*16 + quad*4 + r;
                        float v = a1[mf][nf][r] + cb; v = v > 0.f ? v : 0.f;
                        w11L[t*72 + o] = (__bf16)v;
                    }
            }
        } else {
            #pragma unroll
            for (int nf = 0; nf < 4; ++nf) {
                int o = nf*16 + ln;
                float cb = bsel[o];
                #pragma unroll
                for (int mf = 0; mf < 2; ++mf) {
                    bf16x4 pk;
                    #pragma unroll
                    for (int r = 0; r < 4; ++r) {
                        float v = a1[mf][nf][r] + cb; v = v > 0.f ? v : 0.f;
                        pk[r] = (__bf16)v;
                    }
                    *(bf16x4*)(w21T + o*72 + wt + mf*16 + quad*4) = pk;
                }
            }
        }
    }
    __syncthreads();

    // hoist P2 bias (keeps P2 free of vector-global loads -> clean vmcnt ledger)
    float c12v[2];
    #pragma unroll
    for (int nf = 0; nf < 2; ++nf) c12v[nf] = b12[ob + nf*16 + ln];

    // async B-chunk stager: chunk c = K=128 = 16 groups of 1 KB (tail c=32: 8).
    // Own loads per call: 4 (c<32) or 2 (c==32).
    auto stage = [&](int c) {
        const int ng = (c == 32) ? 8 : 16;
        char* buf = smem + (c % 3) * 16384;
        for (int g = wv; g < ng; g += 4) {
            const __bf16* gsrc = Bt22 + ((long)c * 8192 + g * 512) + lane * 8;
            void* ldst = buf + g * 1024;    // wave-uniform base; HW adds lane*16
            __builtin_amdgcn_global_load_lds(
                (const __attribute__((address_space(1))) uint32_t*)gsrc,
                (__attribute__((address_space(3))) uint32_t*)ldst, 16, 0, 0);
        }
    };
    stage(0); stage(1);   // overlap with P2 (catL dead; bufs 0/1 overlay it)

    // ---------- P2: w12 = w11@W12 + b12 (no relu), quarter per wave ----------
    {
        f32x4 a12c[2][2] = {};
        #pragma unroll
        for (int kb = 0; kb < 2; ++kb) {
            bf16x8 af[2];
            #pragma unroll
            for (int mf = 0; mf < 2; ++mf)
                af[mf] = *(const bf16x8*)(w11L + (wt + mf*16 + ln)*72 + kb*32 + quad*8);
            #pragma unroll
            for (int nf = 0; nf < 2; ++nf) {
                bf16x8 bw = *(const bf16x8*)(W12bt + ((kb*4 + quad)*64 + ob + nf*16 + ln)*8);
                #pragma unroll
                for (int mf = 0; mf < 2; ++mf)
                    a12c[mf][nf] = MFMA16(af[mf], bw, a12c[mf][nf]);
            }
        }
        #pragma unroll
        for (int nf = 0; nf < 2; ++nf) {
            int o = ob + nf*16 + ln;
            #pragma unroll
            for (int mf = 0; mf < 2; ++mf)
                #pragma unroll
                for (int r = 0; r < 4; ++r) {
                    int t = wt + mf*16 + quad*4 + r;
                    w12L[t*72 + o] = (__bf16)(a12c[mf][nf][r] + c12v[nf]);
                }
        }
    }
    // chunk-0 own loads drained (stage(1)'s 4 stay in flight); LDS writes visible.
    asm volatile("s_waitcnt vmcnt(4) lgkmcnt(0)\n\ts_barrier" ::: "memory");

    // w12 A-fragments: the constant MFMA A-operand for the whole K-loop, and
    // directly the bias-block A-fragments.
    bf16x8 a12[2][2];
    #pragma unroll
    for (int mf = 0; mf < 2; ++mf)
        #pragma unroll
        for (int sub = 0; sub < 2; ++sub)
            a12[mf][sub] = *(const bf16x8*)(w12L + (wt + mf*16 + ln)*72 + sub*32 + quad*8);

    // ---------- P3: K-loop, depth-2 pipeline, 33 chunks (32 + bias tail) ----------
    f32x4 acc[2][2] = {};
    for (int c = 0; c <= 32; ++c) {
        if (c <= 30) stage(c + 2);
        const __bf16* buf = (const __bf16*)(smem + (c % 3) * 16384);
        if (c < 32) {
            #pragma unroll
            for (int jj = 0; jj < 2; ++jj) {
                const int j = c*2 + jj;
                f32x4 w4[2];
                #pragma unroll
                for (int mf = 0; mf < 2; ++mf) {
                    bf16x4 wv4 = *(const bf16x4*)(w21T + j*72 + wt + mf*16 + quad*4);
                    w4[mf] = __builtin_convertvector(wv4, f32x4);
                }
                #pragma unroll
                for (int nf = 0; nf < 2; ++nf) {
                    bf16x8 bf0 = *(const bf16x8*)(buf + (jj*8     + quad)*512 + (ob + nf*16 + ln)*8);
                    bf16x8 bf1 = *(const bf16x8*)(buf + (jj*8 + 4 + quad)*512 + (ob + nf*16 + ln)*8);
                    #pragma unroll
                    for (int mf = 0; mf < 2; ++mf) {
                        f32x4 fz = {};
                        f32x4 m = MFMA16(a12[mf][0], bf0, fz);
                        m = MFMA16(a12[mf][1], bf1, m);
                        #pragma unroll
                        for (int r = 0; r < 4; ++r)
                            acc[mf][nf][r] = fmaf(w4[mf][r], m[r], acc[mf][nf][r]);
                    }
                }
            }
        } else {
            // bias rows: A = w12 directly, weight 1
            #pragma unroll
            for (int sub = 0; sub < 2; ++sub)
                #pragma unroll
                for (int nf = 0; nf < 2; ++nf) {
                    bf16x8 bfr = *(const bf16x8*)(buf + (sub*4 + quad)*512 + (ob + nf*16 + ln)*8);
                    #pragma unroll
                    for (int mf = 0; mf < 2; ++mf)
                        acc[mf][nf] = MFMA16(a12[mf][sub], bfr, acc[mf][nf]);
                }
        }
        // drain own (c+1) loads only; (c+2) loads stay in flight across barrier
        if (c <= 29)      SYNC_PIPE(4);
        else if (c == 30) SYNC_PIPE(2);
        else if (c == 31) SYNC_PIPE(0);
    }

    // ---------- P4: LayerNorm(64) + relu (o split across waves -> LDS partials) ----------
    #pragma unroll
    for (int mf = 0; mf < 2; ++mf)
        #pragma unroll
        for (int r = 0; r < 4; ++r) {
            float s1 = 0.f, s2 = 0.f;
            #pragma unroll
            for (int nf = 0; nf < 2; ++nf) { float v = acc[mf][nf][r]; s1 += v; s2 += v*v; }
            #pragma unroll
            for (int d = 1; d < 16; d <<= 1) {   // reduce over the 16 lanes of this quad
                s1 += __shfl_xor(s1, d, 64);
                s2 += __shfl_xor(s2, d, 64);
            }
            if (ln == 0) {
                int t = wt + mf*16 + quad*4 + r;
                ps[t*2 + oh] = make_float2(s1, s2);
            }
        }
    __syncthreads();

    float gv[2], bv[2], b3v[2];
    #pragma unroll
    for (int nf = 0; nf < 2; ++nf) {
        int o = ob + nf*16 + ln;
        gv[nf] = ln_g[o]; bv[nf] = ln_b[o]; b3v[nf] = b3[o];
    }
    __bf16* xL = w12L;   // reuse (a12 frags already in registers)
    #pragma unroll
    for (int mf = 0; mf < 2; ++mf)
        #pragma unroll
        for (int r = 0; r < 4; ++r) {
            int t = wt + mf*16 + quad*4 + r;
            float2 p0 = ps[t*2], p1 = ps[t*2 + 1];
            float mean = (p0.x + p1.x) * 0.015625f;
            float var  = (p0.y + p1.y) * 0.015625f - mean * mean;
            float inv  = rsqrtf(var + 1e-5f);
            #pragma unroll
            for (int nf = 0; nf < 2; ++nf) {
                float v = (acc[mf][nf][r] - mean) * inv * gv[nf] + bv[nf];
                v = v > 0.f ? v : 0.f;
                xL[t*72 + ob + nf*16 + ln] = (__bf16)v;
            }
        }
    __syncthreads();

    // ---------- P5: out = x @ W3 + b3 (quarter per wave) ----------
    f32x4 a3[2][2] = {};
    #pragma unroll
    for (int kb = 0; kb < 2; ++kb) {
        bf16x8 af[2];
        #pragma unroll
        for (int mf = 0; mf < 2; ++mf)
            af[mf] = *(const bf16x8*)(xL + (wt + mf*16 + ln)*72 + kb*32 + quad*8);
        #pragma unroll
        for (int nf = 0; nf < 2; ++nf) {
            bf16x8 bfr = *(const bf16x8*)(W3bt + ((kb*4 + quad)*64 + ob + nf*16 + ln)*8);
            #pragma unroll
            for (int mf = 0; mf < 2; ++mf)
                a3[mf][nf] = MFMA16(af[mf], bfr, a3[mf][nf]);
        }
    }
    #pragma unroll
    for (int mf = 0; mf < 2; ++mf)
        #pragma unroll
        for (int nf = 0; nf < 2; ++nf)
            #pragma unroll
            for (int r = 0; r < 4; ++r) {
                long t = tb + wt + mf*16 + quad*4 + r;
                out[t*64 + ob + nf*16 + ln] = a3[mf][nf][r] + b3v[nf];
            }
}

extern "C" void kernel_launch(void* const* d_in, const int* in_sizes, int n_in,
                              void* d_out, int out_size, void* d_ws, size_t ws_size,
                              hipStream_t stream)
{
    const float* img  = (const float*)d_in[0];
    const float* loc  = (const float*)d_in[1];
    const float* W11  = (const float*)d_in[2];
    const float* b11  = (const float*)d_in[3];
    const float* W12  = (const float*)d_in[4];
    const float* b12  = (const float*)d_in[5];
    const float* W21  = (const float*)d_in[6];
    const float* b21  = (const float*)d_in[7];
    const float* W22  = (const float*)d_in[8];
    const float* b22  = (const float*)d_in[9];
    const float* ln_g = (const float*)d_in[10];
    const float* ln_b = (const float*)d_in[11];
    const float* W3   = (const float*)d_in[12];
    const float* b3   = (const float*)d_in[13];
    __bf16* ws = (__bf16*)d_ws;
    float*  o  = (float*)d_out;

    prep_kernel<<<71, 256, 0, stream>>>(W22, b22, W11, W21, W12, W3, ws);
    main_kernel<<<512, 256, 0, stream>>>(img, loc, b11, b12, b21, ln_g, ln_b, b3, ws, o);
}